// Round 6
// baseline (718.207 us; speedup 1.0000x reference)
//
#include <hip/hip_runtime.h>
#include <hip/hip_fp16.h>
#include <cstdint>

#define DEV static __device__ __forceinline__

typedef _Float16 h2v __attribute__((ext_vector_type(2)));
typedef _Float16 half8 __attribute__((ext_vector_type(8)));
typedef float float4v __attribute__((ext_vector_type(4)));

union U32H2 { uint32_t u; _Float16 f[2]; };

DEV uint32_t pack_f2(float a, float b) {
    auto p = __builtin_amdgcn_cvt_pkrtz(a, b);
    return __builtin_bit_cast(uint32_t, p);
}

DEV half8 bc8(uint4 v) { return __builtin_bit_cast(half8, v); }

DEV float fdot2(uint32_t a, uint32_t b, float c) {
    return __builtin_amdgcn_fdot2(__builtin_bit_cast(h2v, a),
                                  __builtin_bit_cast(h2v, b), c, false);
}

DEV void gl_lds16(const void* gsrc, void* ldst) {
    __builtin_amdgcn_global_load_lds(
        (const __attribute__((address_space(1))) uint32_t*)gsrc,
        (__attribute__((address_space(3))) uint32_t*)ldst, 16, 0, 0);
}

// ---------------- workspace layout (uint32 units) ----------------
static const size_t OFF_WV    = 0;          // 98304 : Whh f16 pairs, lane-major [192][512]
static const size_t OFF_GI    = 98304;      // gs: 768 floats
static const size_t OFF_CC    = 99072;
static const size_t OFF_BF    = 99200;
static const size_t OFF_NODES = 164736;
static const size_t OFF_PF    = 263040;
static const size_t OFF_QF    = 459648;
static const size_t OFF_R0    = 656256;
static const size_t OFF_R1    = 680832;
static const size_t OFF_TT    = 705408;
static const size_t OFF_ATT0  = 10142592;
static const size_t OFF_ATT1  = 10290048;
static const size_t OFF_X0    = 10535808;
static const size_t OFF_CS    = 10634112;
static const size_t WS_TOTAL  = 10634816;

// ---------------- prep: WV (Whh -> dot2 lane-major pairs) + gs ----------------
// blocks 0..191: WV[j*512 + t]; j = i*32 + jj. Thread t owns h-elems e0=2*(t>>2),
// e0+1; rows {256*g + e}; k-slice ks=(t&3)*64, pair k=ks+2*jj.
// blocks 192..193: gs (gi + bhh for r,z thirds; gi only for n third)
__global__ void k_prep_wl(const float* __restrict__ Whh, uint32_t* __restrict__ WV,
                          const float* __restrict__ z, const float* __restrict__ Wih,
                          const float* __restrict__ bih, const float* __restrict__ bhh,
                          float* __restrict__ gs) {
    int bb = blockIdx.x, tid = threadIdx.x;
    if (bb < 192) {
        int j = bb;
        int i = j >> 5, jj = j & 31;
        int e0 = 2 * (tid >> 2);
        int e = e0 + (i >= 3 ? 1 : 0);
        int g = (i >= 3) ? i - 3 : i;
        int row = 256*g + e;
        int k = (tid & 3)*64 + 2*jj;
        const float* src = Whh + (size_t)row*256 + k;
        WV[(size_t)j*512 + tid] = pack_f2(src[0], src[1]);
    } else {
        int o = (bb - 192) * 512 + tid;
        if (o < 768) {
            float acc = bih[o];
            if (o < 512) acc += bhh[o];
            for (int i = 0; i < 128; ++i) acc += Wih[o*128 + i] * z[i];
            gs[o] = acc;
        }
    }
}

// ---------------- GRU (block 0, dot2-based) + BF prep (1..128) + cc (129) ----------------
__global__ void __launch_bounds__(512, 2)
k_gru_bf(const float* __restrict__ gs, const float* __restrict__ bhh,
         const uint32_t* __restrict__ WV, float* __restrict__ nodes,
         const float* __restrict__ egW2, const float* __restrict__ egb2,
         const float* __restrict__ a0W1, const float* __restrict__ a1W1,
         uint32_t* __restrict__ BF, float* __restrict__ cc) {
    int bb = blockIdx.x, tid = threadIdx.x;
    if (bb == 0) {
        __shared__ __align__(16) _Float16 hh16[512];   // 2 buffers x 256 f16
        const float L2E = 1.44269504088896f;
        int e0 = 2 * (tid >> 2);
        int e1 = e0 + 1;
        int ks = (tid & 3) * 64;
        bool writer = (tid & 3) == 0;

        // weights: 192 u32 in VGPRs, coalesced lane-major load
        uint32_t w[6][32];
        #pragma unroll
        for (int i = 0; i < 6; ++i)
            #pragma unroll
            for (int j = 0; j < 32; ++j)
                w[i][j] = WV[(size_t)(i*32 + j)*512 + tid];

        float pr0 = -L2E * gs[e0],        pr1 = -L2E * gs[e1];
        float pz0 = -L2E * gs[256 + e0],  pz1 = -L2E * gs[256 + e1];
        float pn0 = -2.f * L2E * gs[512 + e0];
        float pn1 = -2.f * L2E * gs[512 + e1];
        float bn0 = bhh[512 + e0],        bn1 = bhh[512 + e1];

        float h0 = 0.f, h1 = 0.f;
        if (tid < 256) ((uint32_t*)hh16)[tid] = 0u;    // zero both buffers
        __syncthreads();

        int par = 0;
        for (int t = 0; t < 384; ++t) {
            const uint4* hb = (const uint4*)(hh16 + par*256 + ks);
            float a0 = 0.f, a1 = 0.f, a2 = 0.f, a3 = 0.f, a4 = 0.f, a5 = 0.f;
            #pragma unroll
            for (int m = 0; m < 8; ++m) {
                uint4 hv = hb[m];
                uint32_t hu[4] = {hv.x, hv.y, hv.z, hv.w};
                #pragma unroll
                for (int c = 0; c < 4; ++c) {
                    int j = 4*m + c;
                    a0 = fdot2(w[0][j], hu[c], a0);
                    a1 = fdot2(w[1][j], hu[c], a1);
                    a2 = fdot2(w[2][j], hu[c], a2);
                    a3 = fdot2(w[3][j], hu[c], a3);
                    a4 = fdot2(w[4][j], hu[c], a4);
                    a5 = fdot2(w[5][j], hu[c], a5);
                }
            }
            // butterfly over the 4 k-slice lanes
            a0 += __shfl_xor(a0, 1, 64); a0 += __shfl_xor(a0, 2, 64);
            a1 += __shfl_xor(a1, 1, 64); a1 += __shfl_xor(a1, 2, 64);
            a2 += __shfl_xor(a2, 1, 64); a2 += __shfl_xor(a2, 2, 64);
            a3 += __shfl_xor(a3, 1, 64); a3 += __shfl_xor(a3, 2, 64);
            a4 += __shfl_xor(a4, 1, 64); a4 += __shfl_xor(a4, 2, 64);
            a5 += __shfl_xor(a5, 1, 64); a5 += __shfl_xor(a5, 2, 64);

            // gates, fully in-register (a0..a2 = gh r/z/n for e0; a3..a5 for e1)
            float er0 = __builtin_amdgcn_exp2f(__builtin_fmaf(a0, -L2E, pr0));
            float rg0 = __builtin_amdgcn_rcpf(1.f + er0);
            float eu0 = __builtin_amdgcn_exp2f(__builtin_fmaf(a1, -L2E, pz0));
            float u0  = __builtin_amdgcn_rcpf(1.f + eu0);
            float q0  = __builtin_fmaf(rg0 * (a2 + bn0), -2.f * L2E, pn0);
            float e20 = __builtin_amdgcn_exp2f(q0);
            float nn0 = __builtin_fmaf(2.f, __builtin_amdgcn_rcpf(1.f + e20), -1.f);
            h0 = nn0 + u0 * (h0 - nn0);

            float er1 = __builtin_amdgcn_exp2f(__builtin_fmaf(a3, -L2E, pr1));
            float rg1 = __builtin_amdgcn_rcpf(1.f + er1);
            float eu1 = __builtin_amdgcn_exp2f(__builtin_fmaf(a4, -L2E, pz1));
            float u1  = __builtin_amdgcn_rcpf(1.f + eu1);
            float q1  = __builtin_fmaf(rg1 * (a5 + bn1), -2.f * L2E, pn1);
            float e21 = __builtin_amdgcn_exp2f(q1);
            float nn1 = __builtin_fmaf(2.f, __builtin_amdgcn_rcpf(1.f + e21), -1.f);
            h1 = nn1 + u1 * (h1 - nn1);

            if (writer) {
                ((uint32_t*)hh16)[(par ^ 1)*128 + (e0 >> 1)] = pack_f2(h0, h1);
                *(float2*)(nodes + (size_t)t*256 + e0) = make_float2(h0, h1);  // undrained
            }
            asm volatile("s_waitcnt lgkmcnt(0)" ::: "memory");
            __builtin_amdgcn_sched_barrier(0);
            __builtin_amdgcn_s_barrier();
            __builtin_amdgcn_sched_barrier(0);
            par ^= 1;
        }
    } else if (bb < 129) {
        int idx = (bb - 1) * 512 + tid;                // < 65536
        int k2 = idx >> 7, n = idx & 127;
        const float* A = (n < 64) ? (a0W1 + n) : (a1W1 + (n - 64));
        const float* w0 = egW2 + (2*k2) * 128;
        float a = 0.f, b = 0.f;
        for (int i = 0; i < 128; ++i) {
            float av = A[i*64];
            a += w0[i] * av;
            b += w0[128 + i] * av;
        }
        int kk = k2 >> 4, jgrp = (k2 >> 2) & 3, sub = k2 & 3;
        int lane = jgrp*16 + (n & 15), t = n >> 4;
        BF[((kk*8 + t)*64 + lane)*4 + sub] = pack_f2(a, b);
    } else {
        if (tid < 128) {
            const float* A = (tid < 64) ? a0W1 : a1W1;
            int j = tid & 63;
            float acc = 0.f;
            for (int i = 0; i < 128; ++i) acc += egb2[i] * A[i*64 + j];
            cc[tid] = acc;
        }
    }
}

// ---------------- P (A-frag layout), Q (natural f16), R0 ----------------
__global__ void k_pq(const float* __restrict__ nodes, const float* __restrict__ eg_W1,
                     const float* __restrict__ eg_b1, const float* __restrict__ a0W1,
                     const float* __restrict__ a0b1, const float* __restrict__ cc,
                     uint32_t* __restrict__ PF, uint32_t* __restrict__ QF,
                     float* __restrict__ R0) {
    int tid = threadIdx.x;
    int s0 = blockIdx.x * 4;
    __shared__ float ns[4][256];
    #pragma unroll
    for (int q = 0; q < 4; ++q) ns[q][tid] = nodes[(s0+q)*256 + tid];
    __syncthreads();

    int k0 = tid * 4;
    float acc[4][4];
    #pragma unroll
    for (int q = 0; q < 4; ++q) { acc[q][0]=0;acc[q][1]=0;acc[q][2]=0;acc[q][3]=0; }
    for (int i = 0; i < 256; ++i) {
        float4 wv = *(const float4*)&eg_W1[i*1024 + k0];
        #pragma unroll
        for (int q = 0; q < 4; ++q) {
            float nv = ns[q][i];
            acc[q][0] += nv*wv.x; acc[q][1] += nv*wv.y;
            acc[q][2] += nv*wv.z; acc[q][3] += nv*wv.w;
        }
    }
    float4 bv = *(const float4*)&eg_b1[k0];
    {
        int kk = k0 >> 5;
        int lgrp = ((k0 >> 3) & 3) * 16;
        int sub = (k0 & 7) >> 1;                       // 0 or 2
        #pragma unroll
        for (int q = 0; q < 4; ++q) {
            int s = s0 + q, g = s >> 4, srow = s & 15;
            uint2 pw;
            pw.x = pack_f2(acc[q][0] + bv.x, acc[q][1] + bv.y);
            pw.y = pack_f2(acc[q][2] + bv.z, acc[q][3] + bv.w);
            *(uint2*)(PF + (((g*32 + kk)*64 + lgrp + srow) << 2) + sub) = pw;
        }
    }

    #pragma unroll
    for (int q = 0; q < 4; ++q) { acc[q][0]=0;acc[q][1]=0;acc[q][2]=0;acc[q][3]=0; }
    for (int i = 0; i < 256; ++i) {
        float4 wv = *(const float4*)&eg_W1[(256+i)*1024 + k0];
        #pragma unroll
        for (int q = 0; q < 4; ++q) {
            float nv = ns[q][i];
            acc[q][0] += nv*wv.x; acc[q][1] += nv*wv.y;
            acc[q][2] += nv*wv.z; acc[q][3] += nv*wv.w;
        }
    }
    #pragma unroll
    for (int q = 0; q < 4; ++q) {
        uint2 pw;
        pw.x = pack_f2(acc[q][0], acc[q][1]);
        pw.y = pack_f2(acc[q][2], acc[q][3]);
        ((uint2*)QF)[(s0+q)*256 + tid] = pw;           // QF[d][k/2], natural order
    }

    int srow = tid >> 6, j = tid & 63;
    float racc = a0b1[j] + cc[j];
    for (int i = 0; i < 256; ++i) racc += ns[srow][i] * a0W1[(128+i)*64 + j];
    R0[(s0+srow)*64 + j] = racc;
}

// ---------------- phase A (MFMA) + fused att0 ----------------
__global__ void __launch_bounds__(512, 4)
k_phaseA(const uint32_t* __restrict__ PF, const uint32_t* __restrict__ QF,
         const uint32_t* __restrict__ BF, const float* __restrict__ R0,
         const float* __restrict__ a0W2, const float* __restrict__ a0b2,
         uint32_t* __restrict__ TT, float* __restrict__ ATT0) {
    __shared__ __align__(16) char smem[69632];
    uint4* Qs4 = (uint4*)smem;                         // 32 KB
    char* bufbase = smem + 32768;                      // 2 x (2KB P + 16KB B)
    int tid = threadIdx.x;
    int lane = tid & 63, wv = tid >> 6;
    int g = blockIdx.x, dt = blockIdx.y, d0 = dt * 16;

    {
        const char* src = (const char*)(QF + (size_t)d0 * 512);
        for (int off = tid*16; off < 32768; off += 8192)
            gl_lds16(src + off, (char*)Qs4 + off);
    }
    {
        const char* psrc = (const char*)(PF + (size_t)g * 8192);
        if (tid < 128) gl_lds16(psrc + tid*16, bufbase + tid*16);
        const char* bsrc = (const char*)BF;
        #pragma unroll
        for (int i = 0; i < 2; ++i)
            gl_lds16(bsrc + tid*16 + i*8192, bufbase + 2048 + tid*16 + i*8192);
    }
    asm volatile("s_waitcnt vmcnt(0)" ::: "memory");
    __builtin_amdgcn_sched_barrier(0);
    __builtin_amdgcn_s_barrier();
    __builtin_amdgcn_sched_barrier(0);

    float4v acc[2][8];
    #pragma unroll
    for (int t = 0; t < 2; ++t)
        #pragma unroll
        for (int n = 0; n < 8; ++n) acc[t][n] = 0.f;

    for (int hc = 0; hc < 16; ++hc) {
        char* cur = bufbase + (hc & 1) * 18432;
        char* nxt = bufbase + ((hc + 1) & 1) * 18432;
        if (hc < 15) {
            const char* psrc = (const char*)(PF + ((size_t)g*32 + (size_t)(hc+1)*2) * 256);
            if (tid < 128) gl_lds16(psrc + tid*16, nxt + tid*16);
            const char* bsrc = (const char*)(BF + (size_t)(hc+1) * 4096);
            #pragma unroll
            for (int i = 0; i < 2; ++i)
                gl_lds16(bsrc + tid*16 + i*8192, nxt + 2048 + tid*16 + i*8192);
        }
        uint4* Ph = (uint4*)cur;
        uint4* Bh = (uint4*)(cur + 2048);
        #pragma unroll
        for (int kkl = 0; kkl < 2; ++kkl) {
            int kkg = hc*2 + kkl;
            half8 b[8];
            #pragma unroll
            for (int n = 0; n < 8; ++n) b[n] = bc8(Bh[(kkl*8 + n)*64 + lane]);
            half8 p8 = bc8(Ph[kkl*64 + lane]);
            #pragma unroll
            for (int t = 0; t < 2; ++t) {
                half8 q8 = bc8(Qs4[(wv*2 + t)*128 + kkg*4 + (lane >> 4)]);
                half8 x = p8 + q8;
                half8 zz = 0;
                x = __builtin_elementwise_max(x, zz);
                #pragma unroll
                for (int n = 0; n < 8; ++n)
                    acc[t][n] = __builtin_amdgcn_mfma_f32_16x16x32_f16(x, b[n], acc[t][n], 0, 0, 0);
            }
        }
        asm volatile("s_waitcnt vmcnt(0)" ::: "memory");
        __builtin_amdgcn_sched_barrier(0);
        __builtin_amdgcn_s_barrier();
        __builtin_amdgcn_sched_barrier(0);
    }

    __syncthreads();
    float* R0s = (float*)smem;                         // reuse Q region
    float* w2s = (float*)(smem + 4096);
    for (int i = tid; i < 1024; i += 512)
        R0s[i] = R0[(size_t)(g*16 + (i >> 6))*64 + (i & 63)];
    if (tid < 64) w2s[tid] = a0W2[tid];
    float b2v = a0b2[0];

    _Float16* epi = (_Float16*)(smem + 32768);
    int cn = lane & 15, rhi = (lane >> 4) * 4;
    for (int half = 0; half < 2; ++half) {
        __syncthreads();
        #pragma unroll
        for (int t = 0; t < 2; ++t) {
            int dl = wv*2 + t;
            #pragma unroll
            for (int n = 0; n < 4; ++n) {
                int j = n*16 + cn;
                float4v v = acc[t][half*4 + n];
                #pragma unroll
                for (int r = 0; r < 4; ++r)
                    epi[((rhi + r)*16 + dl)*64 + j] = (_Float16)v[r];
            }
        }
        __syncthreads();
        {
            int p = tid >> 1, sub = tid & 1;
            int srow = p >> 4, dl = p & 15;
            const uint4* src = (const uint4*)(epi + (size_t)p*64);
            uint4* dst = (uint4*)(TT + ((size_t)((g*16 + srow)*384 + d0 + dl))*64 + half*32);
            #pragma unroll
            for (int q = 0; q < 4; ++q) dst[sub*4 + q] = src[sub*4 + q];
        }
        if (half == 0 && tid < 256) {
            int sl = tid >> 4, dl = tid & 15;
            const _Float16* tp = epi + (size_t)(sl*16 + dl)*64;
            const float* rp = R0s + sl*64;
            float logit = b2v;
            #pragma unroll
            for (int j = 0; j < 64; ++j)
                logit += fmaxf((float)tp[j] + rp[j], 0.f) * w2s[j];
            float a = 1.f / (1.f + __expf(-logit));
            int s = g*16 + sl, d = d0 + dl;
            ATT0[(size_t)s*384 + d] = (s == d) ? 0.f : a;
        }
    }
}

// ---------------- attention (att1, + fused column-sum) ----------------
__global__ void k_att(const uint32_t* __restrict__ TT, const float* __restrict__ R,
                      const float* __restrict__ w2, const float* __restrict__ b2,
                      int off, float* __restrict__ ATT, float* __restrict__ CS) {
    int tid = threadIdx.x;
    int p = blockIdx.x * 256 + tid;
    int s = p / 384, d = p - s * 384;
    int sa = (blockIdx.x * 256) / 384;
    __shared__ float w2s[64];
    __shared__ float rs[2][64];
    if (tid < 64) w2s[tid] = w2[tid];
    else if (tid < 128) rs[0][tid - 64] = R[sa*64 + (tid - 64)];
    else if (tid < 192) {
        int sb = sa + 1;
        rs[1][tid - 128] = (sb < 384) ? R[sb*64 + (tid - 128)] : 0.f;
    }
    __syncthreads();
    const uint4* tp = (const uint4*)(TT + (size_t)p*64 + off);
    const float* rp = (s == sa) ? rs[0] : rs[1];
    float logit = b2[0];
    #pragma unroll
    for (int m = 0; m < 8; ++m) {
        uint4 tv = tp[m];
        uint32_t us[4] = {tv.x, tv.y, tv.z, tv.w};
        #pragma unroll
        for (int q = 0; q < 4; ++q) {
            U32H2 c; c.u = us[q];
            int j = m*8 + q*2;
            float h0 = fmaxf((float)c.f[0] + rp[j],   0.f);
            float h1 = fmaxf((float)c.f[1] + rp[j+1], 0.f);
            logit += h0*w2s[j] + h1*w2s[j+1];
        }
    }
    float a = 1.f / (1.f + __expf(-logit));
    float a_eff = (s == d) ? 0.f : a;
    ATT[p] = a_eff;

    if (CS) {
        float va = (s == sa) ? a_eff : 0.f;
        float vb = (s != sa) ? a_eff : 0.f;
        #pragma unroll
        for (int o = 32; o > 0; o >>= 1) {
            va += __shfl_down(va, o, 64);
            vb += __shfl_down(vb, o, 64);
        }
        if ((tid & 63) == 0) {
            atomicAdd(&CS[sa], va);
            int sb = sa + 1;
            if (sb < 384) atomicAdd(&CS[sb], vb);
        }
    }
}

// ---------------- fused agg + conv0 linear + R1 (one block per d) ----------------
__global__ void __launch_bounds__(256)
k_aggx0(const float* __restrict__ ATT, const float* __restrict__ X,
        const float* __restrict__ W, const float* __restrict__ b,
        const float* __restrict__ a1W1, const float* __restrict__ a1b1,
        const float* __restrict__ cc,
        float* __restrict__ X0, float* __restrict__ R1) {
    int d = blockIdx.x, tid = threadIdx.x;
    __shared__ float att_col[384];
    __shared__ float ag[256];
    __shared__ float xs[256];
    for (int s = tid; s < 384; s += 256) att_col[s] = ATT[(size_t)s*384 + d];
    __syncthreads();
    float acc = 0.f;
    #pragma unroll 4
    for (int s = 0; s < 384; ++s)
        acc += att_col[s] * X[(size_t)s*256 + tid];
    ag[tid] = acc;
    __syncthreads();
    float x0 = b[tid];
    for (int i = 0; i < 256; ++i) x0 += ag[i] * W[i*256 + tid];
    x0 = fmaxf(x0, 0.f);
    X0[(size_t)d*256 + tid] = x0;
    xs[tid] = x0;
    __syncthreads();
    if (tid < 64) {
        float r = a1b1[tid] + cc[64 + tid];
        for (int i = 0; i < 256; ++i) r += xs[i] * a1W1[(128+i)*64 + tid];
        R1[(size_t)d*64 + tid] = r;
    }
}

// ---------------- fused V + out (single block) ----------------
__global__ void k_vout(const float* __restrict__ CS, const float* __restrict__ X0,
                       const float* __restrict__ W, const float* __restrict__ b,
                       float* __restrict__ out) {
    int tid = threadIdx.x;
    __shared__ float cs[384];
    __shared__ float vs[256];
    for (int q = tid; q < 384; q += 256) cs[q] = CS[q];
    __syncthreads();
    float acc = 0.f;
    for (int s = 0; s < 384; s += 4) {
        acc += cs[s]*X0[s*256 + tid] + cs[s+1]*X0[(s+1)*256 + tid]
             + cs[s+2]*X0[(s+2)*256 + tid] + cs[s+3]*X0[(s+3)*256 + tid];
    }
    vs[tid] = acc;
    __syncthreads();
    float o = 384.f * b[tid];
    for (int i = 0; i < 256; ++i) o += vs[i] * W[i*256 + tid];
    out[tid] = o;
}

extern "C" void kernel_launch(void* const* d_in, const int* in_sizes, int n_in,
                              void* d_out, int out_size, void* d_ws, size_t ws_size,
                              hipStream_t stream) {
    if (ws_size < WS_TOTAL * sizeof(uint32_t)) return;

    const float* z    = (const float*)d_in[0];
    const float* Wih  = (const float*)d_in[1];
    const float* Whh  = (const float*)d_in[2];
    const float* bih  = (const float*)d_in[3];
    const float* bhh  = (const float*)d_in[4];
    const float* egW1 = (const float*)d_in[5];
    const float* egb1 = (const float*)d_in[6];
    const float* egW2 = (const float*)d_in[7];
    const float* egb2 = (const float*)d_in[8];
    const float* a0W1 = (const float*)d_in[9];
    const float* a0b1 = (const float*)d_in[10];
    const float* a0W2 = (const float*)d_in[11];
    const float* a0b2 = (const float*)d_in[12];
    const float* a1W1 = (const float*)d_in[13];
    const float* a1b1 = (const float*)d_in[14];
    const float* a1W2 = (const float*)d_in[15];
    const float* a1b2 = (const float*)d_in[16];
    const float* c0W  = (const float*)d_in[17];
    const float* c0b  = (const float*)d_in[18];
    const float* c1W  = (const float*)d_in[19];
    const float* c1b  = (const float*)d_in[20];

    uint32_t* ws   = (uint32_t*)d_ws;
    uint32_t* WV   = ws + OFF_WV;
    float*    gs   = (float*)(ws + OFF_GI);
    float*    cc   = (float*)(ws + OFF_CC);
    uint32_t* BF   = ws + OFF_BF;
    float*    nodes= (float*)(ws + OFF_NODES);
    uint32_t* PF   = ws + OFF_PF;
    uint32_t* QF   = ws + OFF_QF;
    float*    R0   = (float*)(ws + OFF_R0);
    float*    R1   = (float*)(ws + OFF_R1);
    uint32_t* TT   = ws + OFF_TT;
    float*    ATT0 = (float*)(ws + OFF_ATT0);
    float*    ATT1 = (float*)(ws + OFF_ATT1);
    float*    X0   = (float*)(ws + OFF_X0);
    float*    CS   = (float*)(ws + OFF_CS);
    float*    out  = (float*)d_out;

    hipMemsetAsync(CS, 0, 384 * sizeof(float), stream);
    hipLaunchKernelGGL(k_prep_wl, dim3(194),    dim3(512), 0, stream, Whh, WV, z, Wih, bih, bhh, gs);
    hipLaunchKernelGGL(k_gru_bf,  dim3(130),    dim3(512), 0, stream, gs, bhh, WV, nodes,
                       egW2, egb2, a0W1, a1W1, BF, cc);
    hipLaunchKernelGGL(k_pq,      dim3(96),     dim3(256), 0, stream, nodes, egW1, egb1, a0W1, a0b1, cc, PF, QF, R0);
    hipLaunchKernelGGL(k_phaseA,  dim3(24, 24), dim3(512), 0, stream, PF, QF, BF, R0, a0W2, a0b2, TT, ATT0);
    hipLaunchKernelGGL(k_aggx0,   dim3(384),    dim3(256), 0, stream, ATT0, nodes, c0W, c0b, a1W1, a1b1, cc, X0, R1);
    hipLaunchKernelGGL(k_att,     dim3(576),    dim3(256), 0, stream, TT, R1, a1W2, a1b2, 32, ATT1, CS);
    hipLaunchKernelGGL(k_vout,    dim3(1),      dim3(256), 0, stream, CS, X0, c1W, c1b, out);
}